// Round 6
// baseline (1479.052 us; speedup 1.0000x reference)
//
#include <hip/hip_runtime.h>
#include <math.h>

// SelfAttention B=4,S=4096,H=1024 fp32 — MFMA, fp16-split precision.
// R6: 2-phase double-buffered prefetch (T3-min) on scores/projv/pv.
// Variants:
//  VAR0 PROJQK: 1-phase, f16 {Ah,Al,Bh,Bl}, acc += Ah·Bh + Al·Bh + Ah·Bl; split-f16 out + bias
//  VAR1 PROJV : 2-phase, f16 NT=2, acc += A·B; bf16 transposed out + bias
//  VAR2 SCORES: 2-phase, f16 NT=3 {Ah,Al,Bh}, acc += Ah·Bh + Al·Bh; f32 out
//  VAR3 PV    : 2-phase, bf16 NT=2; f32 out

typedef unsigned short u16;
typedef _Float16 f16x8 __attribute__((ext_vector_type(8)));
typedef __bf16 bf16x8 __attribute__((ext_vector_type(8)));
typedef float f32x4 __attribute__((ext_vector_type(4)));
struct __align__(8) u16x4 { u16 x, y, z, w; };

__device__ __forceinline__ u16 f2bf(float f) {
    unsigned u = __builtin_bit_cast(unsigned, f);
    u += 0x7fffu + ((u >> 16) & 1u);
    return (u16)(u >> 16);
}
__device__ __forceinline__ u16 f2h(float f) {
    _Float16 h = (_Float16)f;
    return __builtin_bit_cast(u16, h);
}
__device__ __forceinline__ float h2f(u16 h) {
    return (float)__builtin_bit_cast(_Float16, h);
}

#define MF16(a, b, c) __builtin_amdgcn_mfma_f32_16x16x32_f16( \
    __builtin_bit_cast(f16x8, a), __builtin_bit_cast(f16x8, b), c, 0, 0, 0)
#define MBF16(a, b, c) __builtin_amdgcn_mfma_f32_16x16x32_bf16(a, b, c, 0, 0, 0)

// Batch-blocked q/k/P region geometry (u16 elements).
#define SLOT_E  (4u * 1024 * 1024)        // 8 MiB
#define BBLK_E  (16u * 1024 * 1024)       // 32 MiB per batch block

#define GEMM_PARAMS const u16* __restrict__ A0, const u16* __restrict__ A1, \
    const u16* __restrict__ B0, const u16* __restrict__ B1, \
    int K, int lda, int ldb, const float* __restrict__ bias, \
    float* __restrict__ Cf, u16* __restrict__ Ch, u16* __restrict__ Cl, \
    int ldc, int nbx, unsigned long long zsA, unsigned long long zsB, \
    unsigned long long zsC

template<int VAR>
__device__ __forceinline__ void gemm_body(GEMM_PARAMS)
{
    constexpr bool TWOPH = (VAR != 0);
    constexpr int NT = (VAR == 0) ? 4 : (VAR == 2) ? 3 : 2;   // [128][32] tiles/step
    constexpr int BUFB = NT * 8192;
    constexpr int LDSB = (TWOPH ? 2 : 1) * BUFB;
    __shared__ char lds[LDSB];

    // XCD-aware bijective swizzle (gridDim.x % 8 == 0 for all our grids).
    const int cpx = (int)gridDim.x >> 3;
    const int raw = blockIdx.x;
    const int swz = (raw & 7) * cpx + (raw >> 3);
    const int bm = (swz / nbx) * 128, bn = (swz % nbx) * 128;

    const unsigned long long z = blockIdx.z;
    A0 += z * zsA;
    if (A1) A1 += z * zsA;
    B0 += z * zsB;
    if (B1) B1 += z * zsB;

    const int t = threadIdx.x;
    const int w = t >> 6, lane = t & 63;
    const int wr = w >> 1, wc = w & 1;
    const int r16 = lane & 15, g = lane >> 4;

    f32x4 acc[4][4];
#pragma unroll
    for (int i = 0; i < 4; ++i)
#pragma unroll
        for (int j = 0; j < 4; ++j) acc[i][j] = (f32x4)0.0f;

    // Stage NT [128][32] tiles at LDS byte offset bufo; kseg-XOR swizzle via
    // pre-swizzled global source (linear LDS dest, wave-uniform base).
    auto STAGE = [&](int bufo, int k0) {
#pragma unroll
        for (int i = 0; i < NT * 2; ++i) {
            const int ch = w * (NT * 2) + i;
            const int tt = ch >> 3, sub = ch & 7;
            const int s = sub * 64 + lane;
            const int row = s >> 2;
            const int kg = (s & 3) ^ ((row >> 1) & 3);
            const u16* P;
            if constexpr (VAR == 0) P = (tt == 0) ? A0 : (tt == 1) ? A1 : (tt == 2) ? B0 : B1;
            else if constexpr (VAR == 2) P = (tt == 0) ? A0 : (tt == 1) ? A1 : B0;
            else P = (tt == 0) ? A0 : B0;
            const int rb = (tt < NT - 1 || NT == 2 ? (tt == 0 ? bm : (NT == 2 ? bn : bm)) : bn);
            // simpler: A-tiles are tt < (NT==2?1:2) ... keep explicit below
            (void)rb;
            const int isA = (VAR == 0) ? (tt < 2) : (VAR == 2) ? (tt < 2) : (tt < 1);
            const int rbase = isA ? bm : bn;
            const int ld = isA ? lda : ldb;
            __builtin_amdgcn_global_load_lds(
                (const __attribute__((address_space(1))) void*)
                    (P + (size_t)(rbase + row) * ld + k0 + kg * 8),
                (__attribute__((address_space(3))) void*)(lds + bufo + ch * 1024),
                16, 0, 0);
        }
    };

    // Read fragments from buffer at bufo and issue MFMAs.
    auto COMPUTE = [&](int bufo) {
        constexpr int NA = (VAR == 0 || VAR == 2) ? 2 : 1;
        constexpr int NB = (VAR == 0) ? 2 : 1;
        bf16x8 fa[NA][4], fb[NB][4];
#pragma unroll
        for (int i = 0; i < 4; ++i) {
            const int ra = wr * 64 + i * 16 + r16;
            const int oa = ra * 64 + ((g ^ ((ra >> 1) & 3)) << 4);
#pragma unroll
            for (int a = 0; a < NA; ++a)
                fa[a][i] = *(const bf16x8*)(lds + bufo + a * 8192 + oa);
            const int rbw = wc * 64 + i * 16 + r16;
            const int ob = rbw * 64 + ((g ^ ((rbw >> 1) & 3)) << 4);
#pragma unroll
            for (int b = 0; b < NB; ++b)
                fb[b][i] = *(const bf16x8*)(lds + bufo + (NA + b) * 8192 + ob);
        }
#pragma unroll
        for (int i = 0; i < 4; ++i)
#pragma unroll
            for (int j = 0; j < 4; ++j) {
                if constexpr (VAR == 0) {
                    acc[i][j] = MF16(fa[0][i], fb[0][j], acc[i][j]);
                    acc[i][j] = MF16(fa[1][i], fb[0][j], acc[i][j]);
                    acc[i][j] = MF16(fa[0][i], fb[1][j], acc[i][j]);
                } else if constexpr (VAR == 2) {
                    acc[i][j] = MF16(fa[0][i], fb[0][j], acc[i][j]);
                    acc[i][j] = MF16(fa[1][i], fb[0][j], acc[i][j]);
                } else if constexpr (VAR == 1) {
                    acc[i][j] = MF16(fa[0][i], fb[0][j], acc[i][j]);
                } else {
                    acc[i][j] = MBF16(fa[0][i], fb[0][j], acc[i][j]);
                }
            }
    };

    if constexpr (TWOPH) {
        // 2-phase double-buffered prefetch: one __syncthreads per K-step.
        // Safety: syncthreads = waitcnt vmcnt(0) lgkmcnt(0) + s_barrier, so all
        // waves' ds_reads of buf[t&1] drain before anyone stages into it at t+1.
        const int nk = K >> 5;
        STAGE(0, 0);
        __syncthreads();
        for (int tt = 0; tt < nk; ++tt) {
            if (tt + 1 < nk) STAGE(((tt + 1) & 1) * BUFB, (tt + 1) << 5);
            COMPUTE((tt & 1) * BUFB);
            __syncthreads();
        }
    } else {
        for (int k0 = 0; k0 < K; k0 += 32) {
            STAGE(0, k0);
            __syncthreads();
            COMPUTE(0);
            __syncthreads();
        }
    }

    // ---- epilogue: C/D layout col=lane&15, row=(lane>>4)*4+reg ----
#pragma unroll
    for (int j = 0; j < 4; ++j) {
        const int gc = bn + wc * 64 + j * 16 + r16;
        const float bv = bias ? bias[gc] : 0.0f;
#pragma unroll
        for (int i = 0; i < 4; ++i) {
            const int gr = bm + wr * 64 + i * 16 + g * 4;
#pragma unroll
            for (int r = 0; r < 4; ++r) {
                const float val = acc[i][j][r] + bv;
                const int grr = gr + r;
                if constexpr (VAR == 0) {
                    // batch-blocked split-f16 write (row = grr)
                    const size_t bb = (size_t)(grr >> 12) * BBLK_E;
                    const size_t idx = bb + (size_t)(grr & 4095) * ldc + gc;
                    const u16 hh = f2h(val);
                    Ch[idx] = hh;
                    if (Cl) Cl[idx] = f2h(val - h2f(hh));
                } else if constexpr (VAR == 1) {
                    Ch[(size_t)gc * ldc + grr] = f2bf(val);   // transposed
                } else {
                    Cf[z * zsC + (size_t)grr * ldc + gc] = val;
                }
            }
        }
    }
}

__global__ __launch_bounds__(256) void gemm_projq(GEMM_PARAMS) { gemm_body<0>(A0,A1,B0,B1,K,lda,ldb,bias,Cf,Ch,Cl,ldc,nbx,zsA,zsB,zsC); }
__global__ __launch_bounds__(256) void gemm_projk(GEMM_PARAMS) { gemm_body<0>(A0,A1,B0,B1,K,lda,ldb,bias,Cf,Ch,Cl,ldc,nbx,zsA,zsB,zsC); }
__global__ __launch_bounds__(256) void gemm_projv(GEMM_PARAMS) { gemm_body<1>(A0,A1,B0,B1,K,lda,ldb,bias,Cf,Ch,Cl,ldc,nbx,zsA,zsB,zsC); }
__global__ __launch_bounds__(256) void gemm_scores(GEMM_PARAMS){ gemm_body<2>(A0,A1,B0,B1,K,lda,ldb,bias,Cf,Ch,Cl,ldc,nbx,zsA,zsB,zsC); }
__global__ __launch_bounds__(256) void gemm_pv(GEMM_PARAMS)    { gemm_body<3>(A0,A1,B0,B1,K,lda,ldb,bias,Cf,Ch,Cl,ldc,nbx,zsA,zsB,zsC); }

// fp32 -> fp16 (hi, lo) elementwise over float4 groups.
__global__ __launch_bounds__(256) void split_h(
    const float* __restrict__ in, u16* __restrict__ hi, u16* __restrict__ lo, int n4)
{
    const int i = blockIdx.x * 256 + threadIdx.x;
    if (i >= n4) return;
    const float4 v = ((const float4*)in)[i];
    u16x4 h, l;
    h.x = f2h(v.x); l.x = f2h(v.x - h2f(h.x));
    h.y = f2h(v.y); l.y = f2h(v.y - h2f(h.y));
    h.z = f2h(v.z); l.z = f2h(v.z - h2f(h.z));
    h.w = f2h(v.w); l.w = f2h(v.w - h2f(h.w));
    ((u16x4*)hi)[i] = h;
    ((u16x4*)lo)[i] = l;
}

// Row softmax over 4096 fp32 -> bf16 P. One 256-thread block per row.
__global__ __launch_bounds__(256) void softmax4096(
    const float* __restrict__ S, u16* __restrict__ P)
{
    const float* p = S + (size_t)blockIdx.x * 4096;
    u16* q = P + (size_t)blockIdx.x * 4096;
    const int t = threadIdx.x;
    const int wave = t >> 6, lane = t & 63;
    __shared__ float red[8];

    float4 v[4];
    float mx = -INFINITY;
#pragma unroll
    for (int i = 0; i < 4; ++i) {
        v[i] = ((const float4*)p)[i * 256 + t];
        mx = fmaxf(mx, fmaxf(fmaxf(v[i].x, v[i].y), fmaxf(v[i].z, v[i].w)));
    }
#pragma unroll
    for (int o = 32; o > 0; o >>= 1) mx = fmaxf(mx, __shfl_xor(mx, o));
    if (lane == 0) red[wave] = mx;
    __syncthreads();
    mx = fmaxf(fmaxf(red[0], red[1]), fmaxf(red[2], red[3]));

    float sum = 0.f;
#pragma unroll
    for (int i = 0; i < 4; ++i) {
        v[i].x = __expf(v[i].x - mx);
        v[i].y = __expf(v[i].y - mx);
        v[i].z = __expf(v[i].z - mx);
        v[i].w = __expf(v[i].w - mx);
        sum += (v[i].x + v[i].y) + (v[i].z + v[i].w);
    }
#pragma unroll
    for (int o = 32; o > 0; o >>= 1) sum += __shfl_xor(sum, o);
    if (lane == 0) red[4 + wave] = sum;
    __syncthreads();
    sum = (red[4] + red[5]) + (red[6] + red[7]);

    const float inv = 1.0f / sum;
#pragma unroll
    for (int i = 0; i < 4; ++i) {
        u16x4 u;
        u.x = f2bf(v[i].x * inv); u.y = f2bf(v[i].y * inv);
        u.z = f2bf(v[i].z * inv); u.w = f2bf(v[i].w * inv);
        ((u16x4*)q)[i * 256 + t] = u;
    }
}

extern "C" void kernel_launch(void* const* d_in, const int* in_sizes, int n_in,
                              void* d_out, int out_size, void* d_ws, size_t ws_size,
                              hipStream_t stream)
{
    const float* x  = (const float*)d_in[0];
    const float* Wq = (const float*)d_in[1];
    const float* bq = (const float*)d_in[2];
    const float* Wk = (const float*)d_in[3];
    const float* bk = (const float*)d_in[4];
    const float* Wv = (const float*)d_in[5];
    const float* bv = (const float*)d_in[6];
    float* out = (float*)d_out;

    const int B = 4, S = 4096, H = 1024;
    const size_t MB = 1u << 20;
    if (ws_size < 256 * MB) return;
    char* wsp = (char*)d_ws;

    // ws layout (256 MiB):
    //  [0,64)    x_hi|x_lo (f16)  -> sc fp32 scratch (attn phase)
    //  [64,192)  batch blocks: per batch 32MiB = {qh|ql|kh|(dead)}; P_b overwrites after softmax_b
    //  [192,224) vT bf16 [1024][16384]
    //  [224,236) W splits (f16 hi/lo x3)
    u16* xh = (u16*)(wsp);
    u16* xl = (u16*)(wsp + 32 * MB);
    float* sc = (float*)(wsp);
    u16* qk = (u16*)(wsp + 64 * MB);
    u16* vT = (u16*)(wsp + 192 * MB);
    u16* Wqh = (u16*)(wsp + 224 * MB), *Wql = (u16*)(wsp + 226 * MB);
    u16* Wkh = (u16*)(wsp + 228 * MB), *Wkl = (u16*)(wsp + 230 * MB);
    u16* Wvh = (u16*)(wsp + 232 * MB), *Wvl = (u16*)(wsp + 234 * MB);

    const dim3 blk(256);
    const u16* nul16 = nullptr;
    float* nulf = nullptr;

    hipLaunchKernelGGL(split_h, dim3(B * S * H / 4 / 256), blk, 0, stream, x, xh, xl, B * S * H / 4);
    hipLaunchKernelGGL(split_h, dim3(H * H / 4 / 256), blk, 0, stream, Wq, Wqh, Wql, H * H / 4);
    hipLaunchKernelGGL(split_h, dim3(H * H / 4 / 256), blk, 0, stream, Wk, Wkh, Wkl, H * H / 4);
    hipLaunchKernelGGL(split_h, dim3(H * H / 4 / 256), blk, 0, stream, Wv, Wvh, Wvl, H * H / 4);

    // ---- projections: grid 1024 blocks (8 x 128), M=16384 ----
    hipLaunchKernelGGL(gemm_projq, dim3(1024), blk, 0, stream,
        xh, xl, Wqh, Wql, H, H, H, bq,
        nulf, qk + 0 * SLOT_E, qk + 1 * SLOT_E, H, 8, 0ull, 0ull, 0ull);
    hipLaunchKernelGGL(gemm_projk, dim3(1024), blk, 0, stream,
        xh, xl, Wkh, Wkl, H, H, H, bk,
        nulf, qk + 2 * SLOT_E, (u16*)nullptr, H, 8, 0ull, 0ull, 0ull);
    hipLaunchKernelGGL(gemm_projv, dim3(1024), blk, 0, stream,
        xh, nul16, Wvh, nul16, H, H, H, bv,
        nulf, vT, (u16*)nullptr, B * S, 8, 0ull, 0ull, 0ull);

    // ---- per-batch scores + softmax (sc scratch shared) ----
    for (int b = 0; b < B; ++b) {
        const u16* qb = qk + (size_t)b * BBLK_E;
        hipLaunchKernelGGL(gemm_scores, dim3(1024), blk, 0, stream,
            qb, qb + SLOT_E, qb + 2 * SLOT_E, nul16,
            H, H, H, (const float*)nullptr,
            sc, (u16*)nullptr, (u16*)nullptr, S, 32, 0ull, 0ull, 0ull);
        hipLaunchKernelGGL(softmax4096, dim3(S), blk, 0, stream,
            sc, qk + (size_t)b * BBLK_E);           // P_b overwrites its block
    }

    // ---- batched PV: grid (256, 1, 4) ----
    hipLaunchKernelGGL(gemm_pv, dim3(256, 1, 4), blk, 0, stream,
        qk, nul16, vT, nul16,
        S, S, B * S, (const float*)nullptr,
        out, (u16*)nullptr, (u16*)nullptr, H, 8,
        (unsigned long long)BBLK_E, 4096ull, (unsigned long long)S * H);
}

// Round 8
// 1432.266 us; speedup vs baseline: 1.0327x; 1.0327x over previous
//
#include <hip/hip_runtime.h>
#include <math.h>
#include <type_traits>

// SelfAttention B=4,S=4096,H=1024 fp32 — MFMA, fp16-split precision.
// R8 = R7 with the unit fix: unrolled STAGE sites pass (tt+1)<<5 / (tt+2)<<5
// (element offset), not the raw tile index. R7 staged K-slices 1,2,3...
// Variants:
//  VAR0 PROJQK: 1-phase, f16 {Ah,Al,Bh,Bl}, acc += Ah·Bh + Al·Bh + Ah·Bl; split-f16 out + bias
//  VAR1 PROJV : 2-phase, f16 NT=2; bf16 transposed out + bias
//  VAR2 SCORES: 2-phase, f16 NT=3 {Ah,Al,Bh}, acc += Ah·Bh + Al·Bh; f32 out
//  VAR3 PV    : 2-phase, bf16 NT=2; f32 out

typedef unsigned short u16;
typedef _Float16 f16x8 __attribute__((ext_vector_type(8)));
typedef __bf16 bf16x8 __attribute__((ext_vector_type(8)));
typedef float f32x4 __attribute__((ext_vector_type(4)));
struct __align__(8) u16x4 { u16 x, y, z, w; };

__device__ __forceinline__ u16 f2bf(float f) {
    unsigned u = __builtin_bit_cast(unsigned, f);
    u += 0x7fffu + ((u >> 16) & 1u);
    return (u16)(u >> 16);
}
__device__ __forceinline__ u16 f2h(float f) {
    _Float16 h = (_Float16)f;
    return __builtin_bit_cast(u16, h);
}
__device__ __forceinline__ float h2f(u16 h) {
    return (float)__builtin_bit_cast(_Float16, h);
}

#define MF16(a, b, c) __builtin_amdgcn_mfma_f32_16x16x32_f16( \
    __builtin_bit_cast(f16x8, a), __builtin_bit_cast(f16x8, b), c, 0, 0, 0)
#define MBF16(a, b, c) __builtin_amdgcn_mfma_f32_16x16x32_bf16(a, b, c, 0, 0, 0)

// Batch-blocked q/k/P region geometry (u16 elements).
#define SLOT_E  (4u * 1024 * 1024)        // 8 MiB
#define BBLK_E  (16u * 1024 * 1024)       // 32 MiB per batch block

#define GEMM_PARAMS const u16* __restrict__ A0, const u16* __restrict__ A1, \
    const u16* __restrict__ B0, const u16* __restrict__ B1, \
    int K, int lda, int ldb, const float* __restrict__ bias, \
    float* __restrict__ Cf, u16* __restrict__ Ch, u16* __restrict__ Cl, \
    int ldc, int nbx, unsigned long long zsA, unsigned long long zsB, \
    unsigned long long zsC

template<int VAR>
__device__ __forceinline__ void gemm_body(GEMM_PARAMS)
{
    constexpr bool TWOPH = (VAR != 0);
    constexpr int NT = (VAR == 0) ? 4 : (VAR == 2) ? 3 : 2;   // [128][32] tiles/step
    constexpr int BUFB = NT * 8192;
    constexpr int LDSB = (TWOPH ? 2 : 1) * BUFB;
    __shared__ char lds[LDSB];

    // XCD-aware bijective swizzle (gridDim.x % 8 == 0 for all our grids).
    const int cpx = (int)gridDim.x >> 3;
    const int raw = blockIdx.x;
    const int swz = (raw & 7) * cpx + (raw >> 3);
    const int bm = (swz / nbx) * 128, bn = (swz % nbx) * 128;

    const unsigned long long z = blockIdx.z;
    A0 += z * zsA;
    if (A1) A1 += z * zsA;
    B0 += z * zsB;
    if (B1) B1 += z * zsB;

    const int t = threadIdx.x;
    const int w = t >> 6, lane = t & 63;
    const int wr = w >> 1, wc = w & 1;
    const int r16 = lane & 15, g = lane >> 4;

    f32x4 acc[4][4];
#pragma unroll
    for (int i = 0; i < 4; ++i)
#pragma unroll
        for (int j = 0; j < 4; ++j) acc[i][j] = (f32x4)0.0f;

    // Stage NT [128][32] tiles at constant LDS byte offset BO; k0 is the
    // K ELEMENT offset. kseg-XOR swizzle via pre-swizzled global source.
    auto STAGE = [&](auto BO, int k0) {
        constexpr int bufo = decltype(BO)::value;
#pragma unroll
        for (int i = 0; i < NT * 2; ++i) {
            const int ch = w * (NT * 2) + i;
            const int tt = ch >> 3, sub = ch & 7;
            const int s = sub * 64 + lane;
            const int row = s >> 2;
            const int kg = (s & 3) ^ ((row >> 1) & 3);
            const u16* P;
            if constexpr (VAR == 0) P = (tt == 0) ? A0 : (tt == 1) ? A1 : (tt == 2) ? B0 : B1;
            else if constexpr (VAR == 2) P = (tt == 0) ? A0 : (tt == 1) ? A1 : B0;
            else P = (tt == 0) ? A0 : B0;
            const int isA = (VAR == 0 || VAR == 2) ? (tt < 2) : (tt < 1);
            const int rbase = isA ? bm : bn;
            const int ld = isA ? lda : ldb;
            __builtin_amdgcn_global_load_lds(
                (const __attribute__((address_space(1))) void*)
                    (P + (size_t)(rbase + row) * ld + k0 + kg * 8),
                (__attribute__((address_space(3))) void*)(lds + bufo + ch * 1024),
                16, 0, 0);
        }
    };

    // Read fragments from constant buffer offset BO and issue MFMAs.
    auto COMPUTE = [&](auto BO) {
        constexpr int bufo = decltype(BO)::value;
        constexpr int NA = (VAR == 0 || VAR == 2) ? 2 : 1;
        constexpr int NB = (VAR == 0) ? 2 : 1;
        bf16x8 fa[NA][4], fb[NB][4];
#pragma unroll
        for (int i = 0; i < 4; ++i) {
            const int ra = wr * 64 + i * 16 + r16;
            const int oa = ra * 64 + ((g ^ ((ra >> 1) & 3)) << 4);
#pragma unroll
            for (int a = 0; a < NA; ++a)
                fa[a][i] = *(const bf16x8*)(lds + bufo + a * 8192 + oa);
            const int rbw = wc * 64 + i * 16 + r16;
            const int ob = rbw * 64 + ((g ^ ((rbw >> 1) & 3)) << 4);
#pragma unroll
            for (int b = 0; b < NB; ++b)
                fb[b][i] = *(const bf16x8*)(lds + bufo + (NA + b) * 8192 + ob);
        }
#pragma unroll
        for (int i = 0; i < 4; ++i)
#pragma unroll
            for (int j = 0; j < 4; ++j) {
                if constexpr (VAR == 0) {
                    acc[i][j] = MF16(fa[0][i], fb[0][j], acc[i][j]);
                    acc[i][j] = MF16(fa[1][i], fb[0][j], acc[i][j]);
                    acc[i][j] = MF16(fa[0][i], fb[1][j], acc[i][j]);
                } else if constexpr (VAR == 2) {
                    acc[i][j] = MF16(fa[0][i], fb[0][j], acc[i][j]);
                    acc[i][j] = MF16(fa[1][i], fb[0][j], acc[i][j]);
                } else if constexpr (VAR == 1) {
                    acc[i][j] = MF16(fa[0][i], fb[0][j], acc[i][j]);
                } else {
                    acc[i][j] = MBF16(fa[0][i], fb[0][j], acc[i][j]);
                }
            }
    };

    std::integral_constant<int, 0> Blo;
    std::integral_constant<int, BUFB> Bhi;

    if constexpr (TWOPH) {
        // 2-phase dbuf, constant offsets, one __syncthreads per K-step.
        const int nk = K >> 5;            // even at all call sites (32/32/128)
        STAGE(Blo, 0);
        __syncthreads();
        for (int tt = 0; tt + 2 <= nk; tt += 2) {
            STAGE(Bhi, (tt + 1) << 5);          // <<5: element offset!
            COMPUTE(Blo);
            __syncthreads();
            if (tt + 2 < nk) STAGE(Blo, (tt + 2) << 5);
            COMPUTE(Bhi);
            __syncthreads();
        }
    } else {
        for (int k0 = 0; k0 < K; k0 += 32) {
            STAGE(Blo, k0);
            __syncthreads();
            COMPUTE(Blo);
            __syncthreads();
        }
    }

    // ---- epilogue: C/D layout col=lane&15, row=(lane>>4)*4+reg ----
#pragma unroll
    for (int j = 0; j < 4; ++j) {
        const int gc = bn + wc * 64 + j * 16 + r16;
        const float bv = bias ? bias[gc] : 0.0f;
#pragma unroll
        for (int i = 0; i < 4; ++i) {
            const int gr = bm + wr * 64 + i * 16 + g * 4;
#pragma unroll
            for (int r = 0; r < 4; ++r) {
                const float val = acc[i][j][r] + bv;
                const int grr = gr + r;
                if constexpr (VAR == 0) {
                    // batch-blocked split-f16 write (row = grr)
                    const size_t bb = (size_t)(grr >> 12) * BBLK_E;
                    const size_t idx = bb + (size_t)(grr & 4095) * ldc + gc;
                    const u16 hh = f2h(val);
                    Ch[idx] = hh;
                    if (Cl) Cl[idx] = f2h(val - h2f(hh));
                } else if constexpr (VAR == 1) {
                    Ch[(size_t)gc * ldc + grr] = f2bf(val);   // transposed
                } else {
                    Cf[z * zsC + (size_t)grr * ldc + gc] = val;
                }
            }
        }
    }
}

__global__ __launch_bounds__(256) void gemm_projq(GEMM_PARAMS) { gemm_body<0>(A0,A1,B0,B1,K,lda,ldb,bias,Cf,Ch,Cl,ldc,nbx,zsA,zsB,zsC); }
__global__ __launch_bounds__(256) void gemm_projk(GEMM_PARAMS) { gemm_body<0>(A0,A1,B0,B1,K,lda,ldb,bias,Cf,Ch,Cl,ldc,nbx,zsA,zsB,zsC); }
__global__ __launch_bounds__(256) void gemm_projv(GEMM_PARAMS) { gemm_body<1>(A0,A1,B0,B1,K,lda,ldb,bias,Cf,Ch,Cl,ldc,nbx,zsA,zsB,zsC); }
__global__ __launch_bounds__(256) void gemm_scores(GEMM_PARAMS){ gemm_body<2>(A0,A1,B0,B1,K,lda,ldb,bias,Cf,Ch,Cl,ldc,nbx,zsA,zsB,zsC); }
__global__ __launch_bounds__(256) void gemm_pv(GEMM_PARAMS)    { gemm_body<3>(A0,A1,B0,B1,K,lda,ldb,bias,Cf,Ch,Cl,ldc,nbx,zsA,zsB,zsC); }

// fp32 -> fp16 (hi, lo) elementwise over float4 groups.
__global__ __launch_bounds__(256) void split_h(
    const float* __restrict__ in, u16* __restrict__ hi, u16* __restrict__ lo, int n4)
{
    const int i = blockIdx.x * 256 + threadIdx.x;
    if (i >= n4) return;
    const float4 v = ((const float4*)in)[i];
    u16x4 h, l;
    h.x = f2h(v.x); l.x = f2h(v.x - h2f(h.x));
    h.y = f2h(v.y); l.y = f2h(v.y - h2f(h.y));
    h.z = f2h(v.z); l.z = f2h(v.z - h2f(h.z));
    h.w = f2h(v.w); l.w = f2h(v.w - h2f(h.w));
    ((u16x4*)hi)[i] = h;
    ((u16x4*)lo)[i] = l;
}

// Row softmax over 4096 fp32 -> bf16 P. One 256-thread block per row.
__global__ __launch_bounds__(256) void softmax4096(
    const float* __restrict__ S, u16* __restrict__ P)
{
    const float* p = S + (size_t)blockIdx.x * 4096;
    u16* q = P + (size_t)blockIdx.x * 4096;
    const int t = threadIdx.x;
    const int wave = t >> 6, lane = t & 63;
    __shared__ float red[8];

    float4 v[4];
    float mx = -INFINITY;
#pragma unroll
    for (int i = 0; i < 4; ++i) {
        v[i] = ((const float4*)p)[i * 256 + t];
        mx = fmaxf(mx, fmaxf(fmaxf(v[i].x, v[i].y), fmaxf(v[i].z, v[i].w)));
    }
#pragma unroll
    for (int o = 32; o > 0; o >>= 1) mx = fmaxf(mx, __shfl_xor(mx, o));
    if (lane == 0) red[wave] = mx;
    __syncthreads();
    mx = fmaxf(fmaxf(red[0], red[1]), fmaxf(red[2], red[3]));

    float sum = 0.f;
#pragma unroll
    for (int i = 0; i < 4; ++i) {
        v[i].x = __expf(v[i].x - mx);
        v[i].y = __expf(v[i].y - mx);
        v[i].z = __expf(v[i].z - mx);
        v[i].w = __expf(v[i].w - mx);
        sum += (v[i].x + v[i].y) + (v[i].z + v[i].w);
    }
#pragma unroll
    for (int o = 32; o > 0; o >>= 1) sum += __shfl_xor(sum, o);
    if (lane == 0) red[4 + wave] = sum;
    __syncthreads();
    sum = (red[4] + red[5]) + (red[6] + red[7]);

    const float inv = 1.0f / sum;
#pragma unroll
    for (int i = 0; i < 4; ++i) {
        u16x4 u;
        u.x = f2bf(v[i].x * inv); u.y = f2bf(v[i].y * inv);
        u.z = f2bf(v[i].z * inv); u.w = f2bf(v[i].w * inv);
        ((u16x4*)q)[i * 256 + t] = u;
    }
}

extern "C" void kernel_launch(void* const* d_in, const int* in_sizes, int n_in,
                              void* d_out, int out_size, void* d_ws, size_t ws_size,
                              hipStream_t stream)
{
    const float* x  = (const float*)d_in[0];
    const float* Wq = (const float*)d_in[1];
    const float* bq = (const float*)d_in[2];
    const float* Wk = (const float*)d_in[3];
    const float* bk = (const float*)d_in[4];
    const float* Wv = (const float*)d_in[5];
    const float* bv = (const float*)d_in[6];
    float* out = (float*)d_out;

    const int B = 4, S = 4096, H = 1024;
    const size_t MB = 1u << 20;
    if (ws_size < 256 * MB) return;
    char* wsp = (char*)d_ws;

    // ws layout (256 MiB):
    //  [0,64)    x_hi|x_lo (f16)  -> sc fp32 scratch (attn phase)
    //  [64,192)  batch blocks: per batch 32MiB = {qh|ql|kh|(dead)}; P_b overwrites after softmax_b
    //  [192,224) vT bf16 [1024][16384]
    //  [224,236) W splits (f16 hi/lo x3)
    u16* xh = (u16*)(wsp);
    u16* xl = (u16*)(wsp + 32 * MB);
    float* sc = (float*)(wsp);
    u16* qk = (u16*)(wsp + 64 * MB);
    u16* vT = (u16*)(wsp + 192 * MB);
    u16* Wqh = (u16*)(wsp + 224 * MB), *Wql = (u16*)(wsp + 226 * MB);
    u16* Wkh = (u16*)(wsp + 228 * MB), *Wkl = (u16*)(wsp + 230 * MB);
    u16* Wvh = (u16*)(wsp + 232 * MB), *Wvl = (u16*)(wsp + 234 * MB);

    const dim3 blk(256);
    const u16* nul16 = nullptr;
    float* nulf = nullptr;

    hipLaunchKernelGGL(split_h, dim3(B * S * H / 4 / 256), blk, 0, stream, x, xh, xl, B * S * H / 4);
    hipLaunchKernelGGL(split_h, dim3(H * H / 4 / 256), blk, 0, stream, Wq, Wqh, Wql, H * H / 4);
    hipLaunchKernelGGL(split_h, dim3(H * H / 4 / 256), blk, 0, stream, Wk, Wkh, Wkl, H * H / 4);
    hipLaunchKernelGGL(split_h, dim3(H * H / 4 / 256), blk, 0, stream, Wv, Wvh, Wvl, H * H / 4);

    // ---- projections: grid 1024 blocks (8 x 128), M=16384 ----
    hipLaunchKernelGGL(gemm_projq, dim3(1024), blk, 0, stream,
        xh, xl, Wqh, Wql, H, H, H, bq,
        nulf, qk + 0 * SLOT_E, qk + 1 * SLOT_E, H, 8, 0ull, 0ull, 0ull);
    hipLaunchKernelGGL(gemm_projk, dim3(1024), blk, 0, stream,
        xh, xl, Wkh, Wkl, H, H, H, bk,
        nulf, qk + 2 * SLOT_E, (u16*)nullptr, H, 8, 0ull, 0ull, 0ull);
    hipLaunchKernelGGL(gemm_projv, dim3(1024), blk, 0, stream,
        xh, nul16, Wvh, nul16, H, H, H, bv,
        nulf, vT, (u16*)nullptr, B * S, 8, 0ull, 0ull, 0ull);

    // ---- per-batch scores + softmax (sc scratch shared) ----
    for (int b = 0; b < B; ++b) {
        const u16* qb = qk + (size_t)b * BBLK_E;
        hipLaunchKernelGGL(gemm_scores, dim3(1024), blk, 0, stream,
            qb, qb + SLOT_E, qb + 2 * SLOT_E, nul16,
            H, H, H, (const float*)nullptr,
            sc, (u16*)nullptr, (u16*)nullptr, S, 32, 0ull, 0ull, 0ull);
        hipLaunchKernelGGL(softmax4096, dim3(S), blk, 0, stream,
            sc, qk + (size_t)b * BBLK_E);           // P_b overwrites its block
    }

    // ---- batched PV: grid (256, 1, 4) ----
    hipLaunchKernelGGL(gemm_pv, dim3(256, 1, 4), blk, 0, stream,
        qk, nul16, vT, nul16,
        S, S, B * S, (const float*)nullptr,
        out, (u16*)nullptr, (u16*)nullptr, H, 8,
        (unsigned long long)BBLK_E, 4096ull, (unsigned long long)S * H);
}

// Round 9
// 774.280 us; speedup vs baseline: 1.9102x; 1.8498x over previous
//
#include <hip/hip_runtime.h>
#include <math.h>

// SelfAttention B=4,S=4096,H=1024 fp32 — MFMA, fp16-split precision.
// R9: revert to R5's proven 1-phase structure (2-phase refuted R6-R8:
// global_load_lds is an all-LDS clobber to the compiler + LDS doubling cost
// occupancy). Cut MFMA passes instead — f16 storage of q/k already floors
// δscore at ~0.01, so: proj-qk 3->2 pass, scores 2->1 pass, ql eliminated.
// Variants:
//  VAR0 PROJQK: NT=3 {xh,xl,Wh}, acc += Ah·Bh + Al·Bh; f16 out batch-blocked + bias
//  VAR1 PROJV : NT=2, f16 1 product; bf16 transposed out + bias
//  VAR2 SCORES: NT=2 {qh,kh}, f16 1 product; f32 out
//  VAR3 PV    : NT=2, bf16 1 product; f32 out (z-batched)

typedef unsigned short u16;
typedef _Float16 f16x8 __attribute__((ext_vector_type(8)));
typedef __bf16 bf16x8 __attribute__((ext_vector_type(8)));
typedef float f32x4 __attribute__((ext_vector_type(4)));
struct __align__(8) u16x4 { u16 x, y, z, w; };

__device__ __forceinline__ u16 f2bf(float f) {
    unsigned u = __builtin_bit_cast(unsigned, f);
    u += 0x7fffu + ((u >> 16) & 1u);
    return (u16)(u >> 16);
}
__device__ __forceinline__ u16 f2h(float f) {
    _Float16 h = (_Float16)f;
    return __builtin_bit_cast(u16, h);
}
__device__ __forceinline__ float h2f(u16 h) {
    return (float)__builtin_bit_cast(_Float16, h);
}

#define MF16(a, b, c) __builtin_amdgcn_mfma_f32_16x16x32_f16( \
    __builtin_bit_cast(f16x8, a), __builtin_bit_cast(f16x8, b), c, 0, 0, 0)
#define MBF16(a, b, c) __builtin_amdgcn_mfma_f32_16x16x32_bf16(a, b, c, 0, 0, 0)

// Batch-blocked q/k/P region geometry (u16 elements).
#define SLOT_E  (4u * 1024 * 1024)        // 8 MiB
#define BBLK_E  (16u * 1024 * 1024)       // 32 MiB per batch block

#define GEMM_PARAMS const u16* __restrict__ A0, const u16* __restrict__ A1, \
    const u16* __restrict__ B0, \
    int K, int lda, int ldb, const float* __restrict__ bias, \
    float* __restrict__ Cf, u16* __restrict__ Ch, \
    int ldc, int nbx, unsigned long long zsA, unsigned long long zsB, \
    unsigned long long zsC

template<int VAR>
__device__ __forceinline__ void gemm_body(GEMM_PARAMS)
{
    constexpr int NT = (VAR == 0) ? 3 : 2;            // [128][32] tiles per step
    __shared__ char lds[NT * 8192];

    // XCD-aware bijective swizzle (gridDim.x % 8 == 0 for all our grids).
    const int cpx = (int)gridDim.x >> 3;
    const int raw = blockIdx.x;
    const int swz = (raw & 7) * cpx + (raw >> 3);
    const int bm = (swz / nbx) * 128, bn = (swz % nbx) * 128;

    const unsigned long long z = blockIdx.z;
    A0 += z * zsA;
    if (A1) A1 += z * zsA;
    B0 += z * zsB;

    const int t = threadIdx.x;
    const int w = t >> 6, lane = t & 63;
    const int wr = w >> 1, wc = w & 1;
    const int r16 = lane & 15, g = lane >> 4;

    f32x4 acc[4][4];
#pragma unroll
    for (int i = 0; i < 4; ++i)
#pragma unroll
        for (int j = 0; j < 4; ++j) acc[i][j] = (f32x4)0.0f;

    for (int k0 = 0; k0 < K; k0 += 32) {
        // ---- stage NT [128][32] tiles; kseg-XOR swizzle via pre-swizzled source ----
#pragma unroll
        for (int i = 0; i < NT * 2; ++i) {
            const int ch = w * (NT * 2) + i;          // chunk id, wave-uniform
            const int tt = ch >> 3, sub = ch & 7;
            const int s = sub * 64 + lane;
            const int row = s >> 2;
            const int kg = (s & 3) ^ ((row >> 1) & 3);
            const u16* P;
            if constexpr (VAR == 0) P = (tt == 0) ? A0 : (tt == 1) ? A1 : B0;
            else P = (tt == 0) ? A0 : B0;
            const int isA = (VAR == 0) ? (tt < 2) : (tt < 1);
            const int rbase = isA ? bm : bn;
            const int ld = isA ? lda : ldb;
            __builtin_amdgcn_global_load_lds(
                (const __attribute__((address_space(1))) void*)
                    (P + (size_t)(rbase + row) * ld + k0 + kg * 8),
                (__attribute__((address_space(3))) void*)(lds + ch * 1024),
                16, 0, 0);
        }
        __syncthreads();

        // ---- fragments (swizzled ds_read) ----
        constexpr int NA = (VAR == 0) ? 2 : 1;
        bf16x8 fa[NA][4], fb[4];
#pragma unroll
        for (int i = 0; i < 4; ++i) {
            const int ra = wr * 64 + i * 16 + r16;
            const int oa = ra * 64 + ((g ^ ((ra >> 1) & 3)) << 4);
#pragma unroll
            for (int a = 0; a < NA; ++a)
                fa[a][i] = *(const bf16x8*)(lds + a * 8192 + oa);
            const int rbw = wc * 64 + i * 16 + r16;
            const int ob = rbw * 64 + ((g ^ ((rbw >> 1) & 3)) << 4);
            fb[i] = *(const bf16x8*)(lds + NA * 8192 + ob);
        }

        // ---- products ----
#pragma unroll
        for (int i = 0; i < 4; ++i)
#pragma unroll
            for (int j = 0; j < 4; ++j) {
                if constexpr (VAR == 0) {
                    acc[i][j] = MF16(fa[0][i], fb[j], acc[i][j]);
                    acc[i][j] = MF16(fa[1][i], fb[j], acc[i][j]);
                } else if constexpr (VAR == 1 || VAR == 2) {
                    acc[i][j] = MF16(fa[0][i], fb[j], acc[i][j]);
                } else {
                    acc[i][j] = MBF16(fa[0][i], fb[j], acc[i][j]);
                }
            }
        __syncthreads();
    }

    // ---- epilogue: C/D layout col=lane&15, row=(lane>>4)*4+reg ----
#pragma unroll
    for (int j = 0; j < 4; ++j) {
        const int gc = bn + wc * 64 + j * 16 + r16;
        const float bv = bias ? bias[gc] : 0.0f;
#pragma unroll
        for (int i = 0; i < 4; ++i) {
            const int gr = bm + wr * 64 + i * 16 + g * 4;
#pragma unroll
            for (int r = 0; r < 4; ++r) {
                const float val = acc[i][j][r] + bv;
                const int grr = gr + r;
                if constexpr (VAR == 0) {
                    // batch-blocked single-f16 write (row = grr)
                    const size_t bb = (size_t)(grr >> 12) * BBLK_E;
                    Ch[bb + (size_t)(grr & 4095) * ldc + gc] = f2h(val);
                } else if constexpr (VAR == 1) {
                    Ch[(size_t)gc * ldc + grr] = f2bf(val);   // transposed
                } else {
                    Cf[z * zsC + (size_t)grr * ldc + gc] = val;
                }
            }
        }
    }
}

__global__ __launch_bounds__(256) void gemm_projq(GEMM_PARAMS) { gemm_body<0>(A0,A1,B0,K,lda,ldb,bias,Cf,Ch,ldc,nbx,zsA,zsB,zsC); }
__global__ __launch_bounds__(256) void gemm_projk(GEMM_PARAMS) { gemm_body<0>(A0,A1,B0,K,lda,ldb,bias,Cf,Ch,ldc,nbx,zsA,zsB,zsC); }
__global__ __launch_bounds__(256) void gemm_projv(GEMM_PARAMS) { gemm_body<1>(A0,A1,B0,K,lda,ldb,bias,Cf,Ch,ldc,nbx,zsA,zsB,zsC); }
__global__ __launch_bounds__(256) void gemm_scores(GEMM_PARAMS){ gemm_body<2>(A0,A1,B0,K,lda,ldb,bias,Cf,Ch,ldc,nbx,zsA,zsB,zsC); }
__global__ __launch_bounds__(256) void gemm_pv(GEMM_PARAMS)    { gemm_body<3>(A0,A1,B0,K,lda,ldb,bias,Cf,Ch,ldc,nbx,zsA,zsB,zsC); }

// fp32 -> fp16 (hi, lo) elementwise over float4 groups.
__global__ __launch_bounds__(256) void split_h(
    const float* __restrict__ in, u16* __restrict__ hi, u16* __restrict__ lo, int n4)
{
    const int i = blockIdx.x * 256 + threadIdx.x;
    if (i >= n4) return;
    const float4 v = ((const float4*)in)[i];
    u16x4 h, l;
    h.x = f2h(v.x); l.x = f2h(v.x - h2f(h.x));
    h.y = f2h(v.y); l.y = f2h(v.y - h2f(h.y));
    h.z = f2h(v.z); l.z = f2h(v.z - h2f(h.z));
    h.w = f2h(v.w); l.w = f2h(v.w - h2f(h.w));
    ((u16x4*)hi)[i] = h;
    ((u16x4*)lo)[i] = l;
}

// Row softmax over 4096 fp32 -> bf16 P. One 256-thread block per row.
__global__ __launch_bounds__(256) void softmax4096(
    const float* __restrict__ S, u16* __restrict__ P)
{
    const float* p = S + (size_t)blockIdx.x * 4096;
    u16* q = P + (size_t)blockIdx.x * 4096;
    const int t = threadIdx.x;
    const int wave = t >> 6, lane = t & 63;
    __shared__ float red[8];

    float4 v[4];
    float mx = -INFINITY;
#pragma unroll
    for (int i = 0; i < 4; ++i) {
        v[i] = ((const float4*)p)[i * 256 + t];
        mx = fmaxf(mx, fmaxf(fmaxf(v[i].x, v[i].y), fmaxf(v[i].z, v[i].w)));
    }
#pragma unroll
    for (int o = 32; o > 0; o >>= 1) mx = fmaxf(mx, __shfl_xor(mx, o));
    if (lane == 0) red[wave] = mx;
    __syncthreads();
    mx = fmaxf(fmaxf(red[0], red[1]), fmaxf(red[2], red[3]));

    float sum = 0.f;
#pragma unroll
    for (int i = 0; i < 4; ++i) {
        v[i].x = __expf(v[i].x - mx);
        v[i].y = __expf(v[i].y - mx);
        v[i].z = __expf(v[i].z - mx);
        v[i].w = __expf(v[i].w - mx);
        sum += (v[i].x + v[i].y) + (v[i].z + v[i].w);
    }
#pragma unroll
    for (int o = 32; o > 0; o >>= 1) sum += __shfl_xor(sum, o);
    if (lane == 0) red[4 + wave] = sum;
    __syncthreads();
    sum = (red[4] + red[5]) + (red[6] + red[7]);

    const float inv = 1.0f / sum;
#pragma unroll
    for (int i = 0; i < 4; ++i) {
        u16x4 u;
        u.x = f2bf(v[i].x * inv); u.y = f2bf(v[i].y * inv);
        u.z = f2bf(v[i].z * inv); u.w = f2bf(v[i].w * inv);
        ((u16x4*)q)[i * 256 + t] = u;
    }
}

extern "C" void kernel_launch(void* const* d_in, const int* in_sizes, int n_in,
                              void* d_out, int out_size, void* d_ws, size_t ws_size,
                              hipStream_t stream)
{
    const float* x  = (const float*)d_in[0];
    const float* Wq = (const float*)d_in[1];
    const float* bq = (const float*)d_in[2];
    const float* Wk = (const float*)d_in[3];
    const float* bk = (const float*)d_in[4];
    const float* Wv = (const float*)d_in[5];
    const float* bv = (const float*)d_in[6];
    float* out = (float*)d_out;

    const int B = 4, S = 4096, H = 1024;
    const size_t MB = 1u << 20;
    if (ws_size < 256 * MB) return;
    char* wsp = (char*)d_ws;

    // ws layout (256 MiB):
    //  [0,64)    x_hi|x_lo (f16)  -> sc fp32 scratch (attn phase)
    //  [64,192)  batch blocks: per batch 32MiB = {qh 8|kh 8|16 dead}; P_b overwrites after softmax_b
    //  [192,224) vT bf16 [1024][16384]
    //  [224,236) W splits (f16 hi/lo x3; lo unused, scratch)
    u16* xh = (u16*)(wsp);
    u16* xl = (u16*)(wsp + 32 * MB);
    float* sc = (float*)(wsp);
    u16* qk = (u16*)(wsp + 64 * MB);
    u16* vT = (u16*)(wsp + 192 * MB);
    u16* Wqh = (u16*)(wsp + 224 * MB), *Wql = (u16*)(wsp + 226 * MB);
    u16* Wkh = (u16*)(wsp + 228 * MB), *Wkl = (u16*)(wsp + 230 * MB);
    u16* Wvh = (u16*)(wsp + 232 * MB), *Wvl = (u16*)(wsp + 234 * MB);

    const dim3 blk(256);
    const u16* nul16 = nullptr;
    float* nulf = nullptr;

    hipLaunchKernelGGL(split_h, dim3(B * S * H / 4 / 256), blk, 0, stream, x, xh, xl, B * S * H / 4);
    hipLaunchKernelGGL(split_h, dim3(H * H / 4 / 256), blk, 0, stream, Wq, Wqh, Wql, H * H / 4);
    hipLaunchKernelGGL(split_h, dim3(H * H / 4 / 256), blk, 0, stream, Wk, Wkh, Wkl, H * H / 4);
    hipLaunchKernelGGL(split_h, dim3(H * H / 4 / 256), blk, 0, stream, Wv, Wvh, Wvl, H * H / 4);

    // ---- projections: grid 1024 blocks (8 x 128), M=16384, 2-pass ----
    hipLaunchKernelGGL(gemm_projq, dim3(1024), blk, 0, stream,
        xh, xl, Wqh, H, H, H, bq,
        nulf, qk + 0 * SLOT_E, H, 8, 0ull, 0ull, 0ull);
    hipLaunchKernelGGL(gemm_projk, dim3(1024), blk, 0, stream,
        xh, xl, Wkh, H, H, H, bk,
        nulf, qk + 1 * SLOT_E, H, 8, 0ull, 0ull, 0ull);
    hipLaunchKernelGGL(gemm_projv, dim3(1024), blk, 0, stream,
        xh, nul16, Wvh, H, H, H, bv,
        nulf, vT, B * S, 8, 0ull, 0ull, 0ull);

    // ---- per-batch scores (1-pass qh·kh) + softmax (sc scratch shared) ----
    for (int b = 0; b < B; ++b) {
        const u16* qb = qk + (size_t)b * BBLK_E;
        hipLaunchKernelGGL(gemm_scores, dim3(1024), blk, 0, stream,
            qb, nul16, qb + SLOT_E,
            H, H, H, (const float*)nullptr,
            sc, (u16*)nullptr, S, 32, 0ull, 0ull, 0ull);
        hipLaunchKernelGGL(softmax4096, dim3(S), blk, 0, stream,
            sc, qk + (size_t)b * BBLK_E);           // P_b overwrites its block
    }

    // ---- batched PV: grid (256, 1, 4) ----
    hipLaunchKernelGGL(gemm_pv, dim3(256, 1, 4), blk, 0, stream,
        qk, nul16, vT,
        S, S, B * S, (const float*)nullptr,
        out, (u16*)nullptr, H, 8,
        (unsigned long long)BBLK_E, 4096ull, (unsigned long long)S * H);
}

// Round 10
// 706.822 us; speedup vs baseline: 2.0925x; 1.0954x over previous
//
#include <hip/hip_runtime.h>
#include <math.h>

// SelfAttention B=4,S=4096,H=1024 fp32 — MFMA, fp16-split precision.
// R10 = R9 with BK=64 restored for projv/pv (R5-proven) and extended to the
// 1-pass scores. R9 accidentally demoted PV to KSTEP=32 (189->236 µs).
// Variants:
//  VAR0 PROJQK: KSTEP=32 NT=3 {xh,xl,Wh}, acc += Ah·Bh + Al·Bh; f16 out batch-blocked + bias
//  VAR1 PROJV : KSTEP=64 NT=4, f16; bf16 transposed out + bias
//  VAR2 SCORES: KSTEP=64 NT=4 {q@k0,q@k0+32,k@k0,k@k0+32}, f16; f32 out
//  VAR3 PV    : KSTEP=64 NT=4, bf16; f32 out (z-batched)

typedef unsigned short u16;
typedef _Float16 f16x8 __attribute__((ext_vector_type(8)));
typedef __bf16 bf16x8 __attribute__((ext_vector_type(8)));
typedef float f32x4 __attribute__((ext_vector_type(4)));
struct __align__(8) u16x4 { u16 x, y, z, w; };

__device__ __forceinline__ u16 f2bf(float f) {
    unsigned u = __builtin_bit_cast(unsigned, f);
    u += 0x7fffu + ((u >> 16) & 1u);
    return (u16)(u >> 16);
}
__device__ __forceinline__ u16 f2h(float f) {
    _Float16 h = (_Float16)f;
    return __builtin_bit_cast(u16, h);
}
__device__ __forceinline__ float h2f(u16 h) {
    return (float)__builtin_bit_cast(_Float16, h);
}

#define MF16(a, b, c) __builtin_amdgcn_mfma_f32_16x16x32_f16( \
    __builtin_bit_cast(f16x8, a), __builtin_bit_cast(f16x8, b), c, 0, 0, 0)
#define MBF16(a, b, c) __builtin_amdgcn_mfma_f32_16x16x32_bf16(a, b, c, 0, 0, 0)

// Batch-blocked q/k/P region geometry (u16 elements).
#define SLOT_E  (4u * 1024 * 1024)        // 8 MiB
#define BBLK_E  (16u * 1024 * 1024)       // 32 MiB per batch block

#define GEMM_PARAMS const u16* __restrict__ A0, const u16* __restrict__ A1, \
    const u16* __restrict__ B0, \
    int K, int lda, int ldb, const float* __restrict__ bias, \
    float* __restrict__ Cf, u16* __restrict__ Ch, \
    int ldc, int nbx, unsigned long long zsA, unsigned long long zsB, \
    unsigned long long zsC

template<int VAR>
__device__ __forceinline__ void gemm_body(GEMM_PARAMS)
{
    constexpr int KSTEP = (VAR == 0) ? 32 : 64;
    constexpr int NT = (VAR == 0) ? 3 : 4;            // [128][32] tiles per step
    __shared__ char lds[NT * 8192];

    // XCD-aware bijective swizzle (gridDim.x % 8 == 0 for all our grids).
    const int cpx = (int)gridDim.x >> 3;
    const int raw = blockIdx.x;
    const int swz = (raw & 7) * cpx + (raw >> 3);
    const int bm = (swz / nbx) * 128, bn = (swz % nbx) * 128;

    const unsigned long long z = blockIdx.z;
    A0 += z * zsA;
    if (A1) A1 += z * zsA;
    B0 += z * zsB;

    const int t = threadIdx.x;
    const int w = t >> 6, lane = t & 63;
    const int wr = w >> 1, wc = w & 1;
    const int r16 = lane & 15, g = lane >> 4;

    f32x4 acc[4][4];
#pragma unroll
    for (int i = 0; i < 4; ++i)
#pragma unroll
        for (int j = 0; j < 4; ++j) acc[i][j] = (f32x4)0.0f;

    for (int k0 = 0; k0 < K; k0 += KSTEP) {
        // ---- stage NT [128][32] tiles; kseg-XOR swizzle via pre-swizzled source ----
#pragma unroll
        for (int i = 0; i < NT * 2; ++i) {
            const int ch = w * (NT * 2) + i;          // chunk id, wave-uniform
            const int tt = ch >> 3, sub = ch & 7;
            const int s = sub * 64 + lane;
            const int row = s >> 2;
            const int kg = (s & 3) ^ ((row >> 1) & 3);
            const u16* P;
            int ko;
            if constexpr (VAR == 0) {
                P = (tt == 0) ? A0 : (tt == 1) ? A1 : B0;
                ko = 0;
            } else {
                P = (tt < 2) ? A0 : B0;               // tiles: A@k0,A@k0+32,B@k0,B@k0+32
                ko = (tt & 1) * 32;
            }
            const int isA = (VAR == 0) ? (tt < 2) : (tt < 2);
            const int rbase = isA ? bm : bn;
            const int ld = isA ? lda : ldb;
            __builtin_amdgcn_global_load_lds(
                (const __attribute__((address_space(1))) void*)
                    (P + (size_t)(rbase + row) * ld + k0 + ko + kg * 8),
                (__attribute__((address_space(3))) void*)(lds + ch * 1024),
                16, 0, 0);
        }
        __syncthreads();

        // ---- fragments (swizzled ds_read) ----
        constexpr int NA = (VAR == 0) ? 2 : 2;        // VAR0: {xh,xl}; else {A@k0,A@k0+32}
        constexpr int NB = (VAR == 0) ? 1 : 2;
        bf16x8 fa[NA][4], fb[NB][4];
#pragma unroll
        for (int i = 0; i < 4; ++i) {
            const int ra = wr * 64 + i * 16 + r16;
            const int oa = ra * 64 + ((g ^ ((ra >> 1) & 3)) << 4);
#pragma unroll
            for (int a = 0; a < NA; ++a)
                fa[a][i] = *(const bf16x8*)(lds + a * 8192 + oa);
            const int rbw = wc * 64 + i * 16 + r16;
            const int ob = rbw * 64 + ((g ^ ((rbw >> 1) & 3)) << 4);
#pragma unroll
            for (int b = 0; b < NB; ++b)
                fb[b][i] = *(const bf16x8*)(lds + (NA + b) * 8192 + ob);
        }

        // ---- products ----
#pragma unroll
        for (int i = 0; i < 4; ++i)
#pragma unroll
            for (int j = 0; j < 4; ++j) {
                if constexpr (VAR == 0) {
                    acc[i][j] = MF16(fa[0][i], fb[0][j], acc[i][j]);
                    acc[i][j] = MF16(fa[1][i], fb[0][j], acc[i][j]);
                } else if constexpr (VAR == 1 || VAR == 2) {
                    acc[i][j] = MF16(fa[0][i], fb[0][j], acc[i][j]);   // k0
                    acc[i][j] = MF16(fa[1][i], fb[1][j], acc[i][j]);   // k0+32
                } else {
                    acc[i][j] = MBF16(fa[0][i], fb[0][j], acc[i][j]);
                    acc[i][j] = MBF16(fa[1][i], fb[1][j], acc[i][j]);
                }
            }
        __syncthreads();
    }

    // ---- epilogue: C/D layout col=lane&15, row=(lane>>4)*4+reg ----
#pragma unroll
    for (int j = 0; j < 4; ++j) {
        const int gc = bn + wc * 64 + j * 16 + r16;
        const float bv = bias ? bias[gc] : 0.0f;
#pragma unroll
        for (int i = 0; i < 4; ++i) {
            const int gr = bm + wr * 64 + i * 16 + g * 4;
#pragma unroll
            for (int r = 0; r < 4; ++r) {
                const float val = acc[i][j][r] + bv;
                const int grr = gr + r;
                if constexpr (VAR == 0) {
                    // batch-blocked single-f16 write (row = grr)
                    const size_t bb = (size_t)(grr >> 12) * BBLK_E;
                    Ch[bb + (size_t)(grr & 4095) * ldc + gc] = f2h(val);
                } else if constexpr (VAR == 1) {
                    Ch[(size_t)gc * ldc + grr] = f2bf(val);   // transposed
                } else {
                    Cf[z * zsC + (size_t)grr * ldc + gc] = val;
                }
            }
        }
    }
}

__global__ __launch_bounds__(256) void gemm_projq(GEMM_PARAMS) { gemm_body<0>(A0,A1,B0,K,lda,ldb,bias,Cf,Ch,ldc,nbx,zsA,zsB,zsC); }
__global__ __launch_bounds__(256) void gemm_projk(GEMM_PARAMS) { gemm_body<0>(A0,A1,B0,K,lda,ldb,bias,Cf,Ch,ldc,nbx,zsA,zsB,zsC); }
__global__ __launch_bounds__(256) void gemm_projv(GEMM_PARAMS) { gemm_body<1>(A0,A1,B0,K,lda,ldb,bias,Cf,Ch,ldc,nbx,zsA,zsB,zsC); }
__global__ __launch_bounds__(256) void gemm_scores(GEMM_PARAMS){ gemm_body<2>(A0,A1,B0,K,lda,ldb,bias,Cf,Ch,ldc,nbx,zsA,zsB,zsC); }
__global__ __launch_bounds__(256) void gemm_pv(GEMM_PARAMS)    { gemm_body<3>(A0,A1,B0,K,lda,ldb,bias,Cf,Ch,ldc,nbx,zsA,zsB,zsC); }

// fp32 -> fp16 (hi, lo) elementwise over float4 groups.
__global__ __launch_bounds__(256) void split_h(
    const float* __restrict__ in, u16* __restrict__ hi, u16* __restrict__ lo, int n4)
{
    const int i = blockIdx.x * 256 + threadIdx.x;
    if (i >= n4) return;
    const float4 v = ((const float4*)in)[i];
    u16x4 h, l;
    h.x = f2h(v.x); l.x = f2h(v.x - h2f(h.x));
    h.y = f2h(v.y); l.y = f2h(v.y - h2f(h.y));
    h.z = f2h(v.z); l.z = f2h(v.z - h2f(h.z));
    h.w = f2h(v.w); l.w = f2h(v.w - h2f(h.w));
    ((u16x4*)hi)[i] = h;
    ((u16x4*)lo)[i] = l;
}

// Row softmax over 4096 fp32 -> bf16 P. One 256-thread block per row.
__global__ __launch_bounds__(256) void softmax4096(
    const float* __restrict__ S, u16* __restrict__ P)
{
    const float* p = S + (size_t)blockIdx.x * 4096;
    u16* q = P + (size_t)blockIdx.x * 4096;
    const int t = threadIdx.x;
    const int wave = t >> 6, lane = t & 63;
    __shared__ float red[8];

    float4 v[4];
    float mx = -INFINITY;
#pragma unroll
    for (int i = 0; i < 4; ++i) {
        v[i] = ((const float4*)p)[i * 256 + t];
        mx = fmaxf(mx, fmaxf(fmaxf(v[i].x, v[i].y), fmaxf(v[i].z, v[i].w)));
    }
#pragma unroll
    for (int o = 32; o > 0; o >>= 1) mx = fmaxf(mx, __shfl_xor(mx, o));
    if (lane == 0) red[wave] = mx;
    __syncthreads();
    mx = fmaxf(fmaxf(red[0], red[1]), fmaxf(red[2], red[3]));

    float sum = 0.f;
#pragma unroll
    for (int i = 0; i < 4; ++i) {
        v[i].x = __expf(v[i].x - mx);
        v[i].y = __expf(v[i].y - mx);
        v[i].z = __expf(v[i].z - mx);
        v[i].w = __expf(v[i].w - mx);
        sum += (v[i].x + v[i].y) + (v[i].z + v[i].w);
    }
#pragma unroll
    for (int o = 32; o > 0; o >>= 1) sum += __shfl_xor(sum, o);
    if (lane == 0) red[4 + wave] = sum;
    __syncthreads();
    sum = (red[4] + red[5]) + (red[6] + red[7]);

    const float inv = 1.0f / sum;
#pragma unroll
    for (int i = 0; i < 4; ++i) {
        u16x4 u;
        u.x = f2bf(v[i].x * inv); u.y = f2bf(v[i].y * inv);
        u.z = f2bf(v[i].z * inv); u.w = f2bf(v[i].w * inv);
        ((u16x4*)q)[i * 256 + t] = u;
    }
}

extern "C" void kernel_launch(void* const* d_in, const int* in_sizes, int n_in,
                              void* d_out, int out_size, void* d_ws, size_t ws_size,
                              hipStream_t stream)
{
    const float* x  = (const float*)d_in[0];
    const float* Wq = (const float*)d_in[1];
    const float* bq = (const float*)d_in[2];
    const float* Wk = (const float*)d_in[3];
    const float* bk = (const float*)d_in[4];
    const float* Wv = (const float*)d_in[5];
    const float* bv = (const float*)d_in[6];
    float* out = (float*)d_out;

    const int B = 4, S = 4096, H = 1024;
    const size_t MB = 1u << 20;
    if (ws_size < 256 * MB) return;
    char* wsp = (char*)d_ws;

    // ws layout (256 MiB):
    //  [0,64)    x_hi|x_lo (f16)  -> sc fp32 scratch (attn phase)
    //  [64,192)  batch blocks: per batch 32MiB = {qh 8|kh 8|16 dead}; P_b overwrites after softmax_b
    //  [192,224) vT bf16 [1024][16384]
    //  [224,236) W splits (f16 hi/lo x3; lo unused, scratch)
    u16* xh = (u16*)(wsp);
    u16* xl = (u16*)(wsp + 32 * MB);
    float* sc = (float*)(wsp);
    u16* qk = (u16*)(wsp + 64 * MB);
    u16* vT = (u16*)(wsp + 192 * MB);
    u16* Wqh = (u16*)(wsp + 224 * MB), *Wql = (u16*)(wsp + 226 * MB);
    u16* Wkh = (u16*)(wsp + 228 * MB), *Wkl = (u16*)(wsp + 230 * MB);
    u16* Wvh = (u16*)(wsp + 232 * MB), *Wvl = (u16*)(wsp + 234 * MB);

    const dim3 blk(256);
    const u16* nul16 = nullptr;
    float* nulf = nullptr;

    hipLaunchKernelGGL(split_h, dim3(B * S * H / 4 / 256), blk, 0, stream, x, xh, xl, B * S * H / 4);
    hipLaunchKernelGGL(split_h, dim3(H * H / 4 / 256), blk, 0, stream, Wq, Wqh, Wql, H * H / 4);
    hipLaunchKernelGGL(split_h, dim3(H * H / 4 / 256), blk, 0, stream, Wk, Wkh, Wkl, H * H / 4);
    hipLaunchKernelGGL(split_h, dim3(H * H / 4 / 256), blk, 0, stream, Wv, Wvh, Wvl, H * H / 4);

    // ---- projections: grid 1024 blocks (8 x 128), M=16384, 2-pass ----
    hipLaunchKernelGGL(gemm_projq, dim3(1024), blk, 0, stream,
        xh, xl, Wqh, H, H, H, bq,
        nulf, qk + 0 * SLOT_E, H, 8, 0ull, 0ull, 0ull);
    hipLaunchKernelGGL(gemm_projk, dim3(1024), blk, 0, stream,
        xh, xl, Wkh, H, H, H, bk,
        nulf, qk + 1 * SLOT_E, H, 8, 0ull, 0ull, 0ull);
    hipLaunchKernelGGL(gemm_projv, dim3(1024), blk, 0, stream,
        xh, nul16, Wvh, H, H, H, bv,
        nulf, vT, B * S, 8, 0ull, 0ull, 0ull);

    // ---- per-batch scores (1-pass qh·kh, BK=64) + softmax ----
    for (int b = 0; b < B; ++b) {
        const u16* qb = qk + (size_t)b * BBLK_E;
        hipLaunchKernelGGL(gemm_scores, dim3(1024), blk, 0, stream,
            qb, nul16, qb + SLOT_E,
            H, H, H, (const float*)nullptr,
            sc, (u16*)nullptr, S, 32, 0ull, 0ull, 0ull);
        hipLaunchKernelGGL(softmax4096, dim3(S), blk, 0, stream,
            sc, qk + (size_t)b * BBLK_E);           // P_b overwrites its block
    }

    // ---- batched PV: grid (256, 1, 4) ----
    hipLaunchKernelGGL(gemm_pv, dim3(256, 1, 4), blk, 0, stream,
        qk, nul16, vT,
        S, S, B * S, (const float*)nullptr,
        out, (u16*)nullptr, H, 8,
        (unsigned long long)BBLK_E, 4096ull, (unsigned long long)S * H);
}

// Round 11
// 691.333 us; speedup vs baseline: 2.1394x; 1.0224x over previous
//
#include <hip/hip_runtime.h>
#include <math.h>

// SelfAttention B=4,S=4096,H=1024 fp32 — MFMA, fp16-split precision.
// R11 = R10 with counted-vmcnt prefetch (raw s_barrier, never vmcnt(0) in loop)
// for projv/scores/pv. KSTEP=32, 2x16KB buffers (occupancy preserved).
// proj-qk (VAR0) unchanged from R10.

typedef unsigned short u16;
typedef _Float16 f16x8 __attribute__((ext_vector_type(8)));
typedef __bf16 bf16x8 __attribute__((ext_vector_type(8)));
typedef float f32x4 __attribute__((ext_vector_type(4)));
struct __align__(8) u16x4 { u16 x, y, z, w; };

__device__ __forceinline__ u16 f2bf(float f) {
    unsigned u = __builtin_bit_cast(unsigned, f);
    u += 0x7fffu + ((u >> 16) & 1u);
    return (u16)(u >> 16);
}
__device__ __forceinline__ u16 f2h(float f) {
    _Float16 h = (_Float16)f;
    return __builtin_bit_cast(u16, h);
}
__device__ __forceinline__ float h2f(u16 h) {
    return (float)__builtin_bit_cast(_Float16, h);
}

#define MF16(a, b, c) __builtin_amdgcn_mfma_f32_16x16x32_f16( \
    __builtin_bit_cast(f16x8, a), __builtin_bit_cast(f16x8, b), c, 0, 0, 0)
#define MBF16(a, b, c) __builtin_amdgcn_mfma_f32_16x16x32_bf16(a, b, c, 0, 0, 0)

// Batch-blocked q/k/P region geometry (u16 elements).
#define SLOT_E  (4u * 1024 * 1024)        // 8 MiB
#define BBLK_E  (16u * 1024 * 1024)       // 32 MiB per batch block

#define GEMM_PARAMS const u16* __restrict__ A0, const u16* __restrict__ A1, \
    const u16* __restrict__ B0, \
    int K, int lda, int ldb, const float* __restrict__ bias, \
    float* __restrict__ Cf, u16* __restrict__ Ch, \
    int ldc, int nbx, unsigned long long zsA, unsigned long long zsB, \
    unsigned long long zsC

// ---------------- VAR0: proj-qk, unchanged R10 1-phase ----------------
__device__ __forceinline__ void gemm_projqk_body(GEMM_PARAMS)
{
    constexpr int NT = 3;
    __shared__ char lds[NT * 8192];

    const int cpx = (int)gridDim.x >> 3;
    const int raw = blockIdx.x;
    const int swz = (raw & 7) * cpx + (raw >> 3);
    const int bm = (swz / nbx) * 128, bn = (swz % nbx) * 128;

    const int t = threadIdx.x;
    const int w = t >> 6, lane = t & 63;
    const int wr = w >> 1, wc = w & 1;
    const int r16 = lane & 15, g = lane >> 4;

    f32x4 acc[4][4];
#pragma unroll
    for (int i = 0; i < 4; ++i)
#pragma unroll
        for (int j = 0; j < 4; ++j) acc[i][j] = (f32x4)0.0f;

    for (int k0 = 0; k0 < K; k0 += 32) {
#pragma unroll
        for (int i = 0; i < NT * 2; ++i) {
            const int ch = w * (NT * 2) + i;
            const int tt = ch >> 3, sub = ch & 7;
            const int s = sub * 64 + lane;
            const int row = s >> 2;
            const int kg = (s & 3) ^ ((row >> 1) & 3);
            const u16* P = (tt == 0) ? A0 : (tt == 1) ? A1 : B0;
            const int isA = (tt < 2);
            const int rbase = isA ? bm : bn;
            const int ld = isA ? lda : ldb;
            __builtin_amdgcn_global_load_lds(
                (const __attribute__((address_space(1))) void*)
                    (P + (size_t)(rbase + row) * ld + k0 + kg * 8),
                (__attribute__((address_space(3))) void*)(lds + ch * 1024),
                16, 0, 0);
        }
        __syncthreads();

        bf16x8 fa[2][4], fb[4];
#pragma unroll
        for (int i = 0; i < 4; ++i) {
            const int ra = wr * 64 + i * 16 + r16;
            const int oa = ra * 64 + ((g ^ ((ra >> 1) & 3)) << 4);
            fa[0][i] = *(const bf16x8*)(lds + oa);
            fa[1][i] = *(const bf16x8*)(lds + 8192 + oa);
            const int rbw = wc * 64 + i * 16 + r16;
            const int ob = rbw * 64 + ((g ^ ((rbw >> 1) & 3)) << 4);
            fb[i] = *(const bf16x8*)(lds + 2 * 8192 + ob);
        }
#pragma unroll
        for (int i = 0; i < 4; ++i)
#pragma unroll
            for (int j = 0; j < 4; ++j) {
                acc[i][j] = MF16(fa[0][i], fb[j], acc[i][j]);
                acc[i][j] = MF16(fa[1][i], fb[j], acc[i][j]);
            }
        __syncthreads();
    }

#pragma unroll
    for (int j = 0; j < 4; ++j) {
        const int gc = bn + wc * 64 + j * 16 + r16;
        const float bv = bias ? bias[gc] : 0.0f;
#pragma unroll
        for (int i = 0; i < 4; ++i) {
            const int gr = bm + wr * 64 + i * 16 + g * 4;
#pragma unroll
            for (int r = 0; r < 4; ++r) {
                const int grr = gr + r;
                const size_t bb = (size_t)(grr >> 12) * BBLK_E;
                Ch[bb + (size_t)(grr & 4095) * ldc + gc] = f2h(acc[i][j][r] + bv);
            }
        }
    }
}

// ---------- VAR 1/2/3: 1-product GEMM, counted-vmcnt 2-buffer pipeline ----------
// Per K-step: {vmcnt(4)+s_barrier -> ds_read frags -> lgkmcnt(0)+s_barrier ->
// issue prefetch(t+2) -> 16 MFMA}. stage(t+1) never drained in-loop.
template<int VAR>   // 1: projv f16->bf16^T+bias; 2: scores f16->f32; 3: pv bf16->f32
__device__ __forceinline__ void gemm_pipe_body(GEMM_PARAMS)
{
    __shared__ char lds[2 * 16384];   // 2 buffers x (A 8KB | B 8KB)

    const int cpx = (int)gridDim.x >> 3;
    const int raw = blockIdx.x;
    const int swz = (raw & 7) * cpx + (raw >> 3);
    const int bm = (swz / nbx) * 128, bn = (swz % nbx) * 128;

    const unsigned long long z = blockIdx.z;
    A0 += z * zsA;
    B0 += z * zsB;

    const int t = threadIdx.x;
    const int w = t >> 6, lane = t & 63;
    const int wr = w >> 1, wc = w & 1;
    const int r16 = lane & 15, g = lane >> 4;

    f32x4 acc[4][4];
#pragma unroll
    for (int i = 0; i < 4; ++i)
#pragma unroll
        for (int j = 0; j < 4; ++j) acc[i][j] = (f32x4)0.0f;

    // Stage one K-step tile pair (A 8KB + B 8KB) into buffer at constant bufo.
    // 4 global_load_lds per wave (vmcnt counts in multiples of 4).
    auto STAGE = [&](auto BO, int k0) {
#pragma unroll
        for (int i = 0; i < 4; ++i) {
            constexpr int bufo = decltype(BO)::value;
            const int ch = w * 4 + i;             // 0..15; 0-7 A, 8-15 B
            const int tt = ch >> 3, sub = ch & 7;
            const int s = sub * 64 + lane;
            const int row = s >> 2;
            const int kg = (s & 3) ^ ((row >> 1) & 3);
            const u16* P = tt ? B0 : A0;
            const int rbase = tt ? bn : bm;
            const int ld = tt ? ldb : lda;
            __builtin_amdgcn_global_load_lds(
                (const __attribute__((address_space(1))) void*)
                    (P + (size_t)(rbase + row) * ld + k0 + kg * 8),
                (__attribute__((address_space(3))) void*)(lds + bufo + ch * 1024),
                16, 0, 0);
        }
    };

    bf16x8 fa[4], fb[4];
    auto FRAGS = [&](auto BO) {
        constexpr int bufo = decltype(BO)::value;
#pragma unroll
        for (int i = 0; i < 4; ++i) {
            const int ra = wr * 64 + i * 16 + r16;
            fa[i] = *(const bf16x8*)(lds + bufo + ra * 64 + ((g ^ ((ra >> 1) & 3)) << 4));
            const int rbw = wc * 64 + i * 16 + r16;
            fb[i] = *(const bf16x8*)(lds + bufo + 8192 + rbw * 64 + ((g ^ ((rbw >> 1) & 3)) << 4));
        }
    };
    auto MM = [&]() {
#pragma unroll
        for (int i = 0; i < 4; ++i)
#pragma unroll
            for (int j = 0; j < 4; ++j) {
                if constexpr (VAR == 3) acc[i][j] = MBF16(fa[i], fb[j], acc[i][j]);
                else                    acc[i][j] = MF16(fa[i], fb[j], acc[i][j]);
            }
    };

    std::integral_constant<int, 0> c0;
    std::integral_constant<int, 16384> c1;

    const int nk = K >> 5;                 // 32 (projv/scores) or 128 (pv); even
    STAGE(c0, 0);
    STAGE(c1, 32);

    for (int tt = 0; tt + 2 < nk; tt += 2) {
        // ---- iter even: compute buf0, prefetch tt+2 into buf0 ----
        asm volatile("s_waitcnt vmcnt(4)\n\ts_barrier" ::: "memory");
        FRAGS(c0);
        asm volatile("s_waitcnt lgkmcnt(0)\n\ts_barrier" ::: "memory");
        STAGE(c0, (tt + 2) << 5);
        MM();
        // ---- iter odd: compute buf1, prefetch tt+3 into buf1 ----
        asm volatile("s_waitcnt vmcnt(4)\n\ts_barrier" ::: "memory");
        FRAGS(c1);
        asm volatile("s_waitcnt lgkmcnt(0)\n\ts_barrier" ::: "memory");
        STAGE(c1, (tt + 3) << 5);
        MM();
    }
    // ---- peeled iter nk-2 (buf0): no prefetch ----
    asm volatile("s_waitcnt vmcnt(4)\n\ts_barrier" ::: "memory");
    FRAGS(c0);
    MM();
    // ---- peeled iter nk-1 (buf1): drain ----
    asm volatile("s_waitcnt vmcnt(0)\n\ts_barrier" ::: "memory");
    FRAGS(c1);
    MM();

    // ---- epilogue: C/D layout col=lane&15, row=(lane>>4)*4+reg ----
#pragma unroll
    for (int j = 0; j < 4; ++j) {
        const int gc = bn + wc * 64 + j * 16 + r16;
        const float bv = bias ? bias[gc] : 0.0f;
#pragma unroll
        for (int i = 0; i < 4; ++i) {
            const int gr = bm + wr * 64 + i * 16 + g * 4;
#pragma unroll
            for (int r = 0; r < 4; ++r) {
                const float val = acc[i][j][r] + bv;
                const int grr = gr + r;
                if constexpr (VAR == 1) {
                    Ch[(size_t)gc * ldc + grr] = f2bf(val);   // transposed
                } else {
                    Cf[z * zsC + (size_t)grr * ldc + gc] = val;
                }
            }
        }
    }
}

__global__ __launch_bounds__(256) void gemm_projq(GEMM_PARAMS) { gemm_projqk_body(A0,A1,B0,K,lda,ldb,bias,Cf,Ch,ldc,nbx,zsA,zsB,zsC); }
__global__ __launch_bounds__(256) void gemm_projk(GEMM_PARAMS) { gemm_projqk_body(A0,A1,B0,K,lda,ldb,bias,Cf,Ch,ldc,nbx,zsA,zsB,zsC); }
__global__ __launch_bounds__(256) void gemm_projv(GEMM_PARAMS) { gemm_pipe_body<1>(A0,A1,B0,K,lda,ldb,bias,Cf,Ch,ldc,nbx,zsA,zsB,zsC); }
__global__ __launch_bounds__(256) void gemm_scores(GEMM_PARAMS){ gemm_pipe_body<2>(A0,A1,B0,K,lda,ldb,bias,Cf,Ch,ldc,nbx,zsA,zsB,zsC); }
__global__ __launch_bounds__(256) void gemm_pv(GEMM_PARAMS)    { gemm_pipe_body<3>(A0,A1,B0,K,lda,ldb,bias,Cf,Ch,ldc,nbx,zsA,zsB,zsC); }

// fp32 -> fp16 (hi, lo) elementwise over float4 groups.
__global__ __launch_bounds__(256) void split_h(
    const float* __restrict__ in, u16* __restrict__ hi, u16* __restrict__ lo, int n4)
{
    const int i = blockIdx.x * 256 + threadIdx.x;
    if (i >= n4) return;
    const float4 v = ((const float4*)in)[i];
    u16x4 h, l;
    h.x = f2h(v.x); l.x = f2h(v.x - h2f(h.x));
    h.y = f2h(v.y); l.y = f2h(v.y - h2f(h.y));
    h.z = f2h(v.z); l.z = f2h(v.z - h2f(h.z));
    h.w = f2h(v.w); l.w = f2h(v.w - h2f(h.w));
    ((u16x4*)hi)[i] = h;
    ((u16x4*)lo)[i] = l;
}

// Row softmax over 4096 fp32 -> bf16 P. One 256-thread block per row.
__global__ __launch_bounds__(256) void softmax4096(
    const float* __restrict__ S, u16* __restrict__ P)
{
    const float* p = S + (size_t)blockIdx.x * 4096;
    u16* q = P + (size_t)blockIdx.x * 4096;
    const int t = threadIdx.x;
    const int wave = t >> 6, lane = t & 63;
    __shared__ float red[8];

    float4 v[4];
    float mx = -INFINITY;
#pragma unroll
    for (int i = 0; i < 4; ++i) {
        v[i] = ((const float4*)p)[i * 256 + t];
        mx = fmaxf(mx, fmaxf(fmaxf(v[i].x, v[i].y), fmaxf(v[i].z, v[i].w)));
    }
#pragma unroll
    for (int o = 32; o > 0; o >>= 1) mx = fmaxf(mx, __shfl_xor(mx, o));
    if (lane == 0) red[wave] = mx;
    __syncthreads();
    mx = fmaxf(fmaxf(red[0], red[1]), fmaxf(red[2], red[3]));

    float sum = 0.f;
#pragma unroll
    for (int i = 0; i < 4; ++i) {
        v[i].x = __expf(v[i].x - mx);
        v[i].y = __expf(v[i].y - mx);
        v[i].z = __expf(v[i].z - mx);
        v[i].w = __expf(v[i].w - mx);
        sum += (v[i].x + v[i].y) + (v[i].z + v[i].w);
    }
#pragma unroll
    for (int o = 32; o > 0; o >>= 1) sum += __shfl_xor(sum, o);
    if (lane == 0) red[4 + wave] = sum;
    __syncthreads();
    sum = (red[4] + red[5]) + (red[6] + red[7]);

    const float inv = 1.0f / sum;
#pragma unroll
    for (int i = 0; i < 4; ++i) {
        u16x4 u;
        u.x = f2bf(v[i].x * inv); u.y = f2bf(v[i].y * inv);
        u.z = f2bf(v[i].z * inv); u.w = f2bf(v[i].w * inv);
        ((u16x4*)q)[i * 256 + t] = u;
    }
}

extern "C" void kernel_launch(void* const* d_in, const int* in_sizes, int n_in,
                              void* d_out, int out_size, void* d_ws, size_t ws_size,
                              hipStream_t stream)
{
    const float* x  = (const float*)d_in[0];
    const float* Wq = (const float*)d_in[1];
    const float* bq = (const float*)d_in[2];
    const float* Wk = (const float*)d_in[3];
    const float* bk = (const float*)d_in[4];
    const float* Wv = (const float*)d_in[5];
    const float* bv = (const float*)d_in[6];
    float* out = (float*)d_out;

    const int B = 4, S = 4096, H = 1024;
    const size_t MB = 1u << 20;
    if (ws_size < 256 * MB) return;
    char* wsp = (char*)d_ws;

    // ws layout (256 MiB):
    //  [0,64)    x_hi|x_lo (f16)  -> sc fp32 scratch (attn phase)
    //  [64,192)  batch blocks: per batch 32MiB = {qh 8|kh 8|16 dead}; P_b overwrites after softmax_b
    //  [192,224) vT bf16 [1024][16384]
    //  [224,236) W splits (f16 hi/lo x3; lo unused, scratch)
    u16* xh = (u16*)(wsp);
    u16* xl = (u16*)(wsp + 32 * MB);
    float* sc = (float*)(wsp);
    u16* qk = (u16*)(wsp + 64 * MB);
    u16* vT = (u16*)(wsp + 192 * MB);
    u16* Wqh = (u16*)(wsp + 224 * MB), *Wql = (u16*)(wsp + 226 * MB);
    u16* Wkh = (u16*)(wsp + 228 * MB), *Wkl = (u16*)(wsp + 230 * MB);
    u16* Wvh = (u16*)(wsp + 232 * MB), *Wvl = (u16*)(wsp + 234 * MB);

    const dim3 blk(256);
    const u16* nul16 = nullptr;
    float* nulf = nullptr;

    hipLaunchKernelGGL(split_h, dim3(B * S * H / 4 / 256), blk, 0, stream, x, xh, xl, B * S * H / 4);
    hipLaunchKernelGGL(split_h, dim3(H * H / 4 / 256), blk, 0, stream, Wq, Wqh, Wql, H * H / 4);
    hipLaunchKernelGGL(split_h, dim3(H * H / 4 / 256), blk, 0, stream, Wk, Wkh, Wkl, H * H / 4);
    hipLaunchKernelGGL(split_h, dim3(H * H / 4 / 256), blk, 0, stream, Wv, Wvh, Wvl, H * H / 4);

    // ---- projections: grid 1024 blocks (8 x 128), M=16384, 2-pass ----
    hipLaunchKernelGGL(gemm_projq, dim3(1024), blk, 0, stream,
        xh, xl, Wqh, H, H, H, bq,
        nulf, qk + 0 * SLOT_E, H, 8, 0ull, 0ull, 0ull);
    hipLaunchKernelGGL(gemm_projk, dim3(1024), blk, 0, stream,
        xh, xl, Wkh, H, H, H, bk,
        nulf, qk + 1 * SLOT_E, H, 8, 0ull, 0ull, 0ull);
    hipLaunchKernelGGL(gemm_projv, dim3(1024), blk, 0, stream,
        xh, nul16, Wvh, H, H, H, bv,
        nulf, vT, B * S, 8, 0ull, 0ull, 0ull);

    // ---- per-batch scores (1-pass qh·kh) + softmax ----
    for (int b = 0; b < B; ++b) {
        const u16* qb = qk + (size_t)b * BBLK_E;
        hipLaunchKernelGGL(gemm_scores, dim3(1024), blk, 0, stream,
            qb, nul16, qb + SLOT_E,
            H, H, H, (const float*)nullptr,
            sc, (u16*)nullptr, S, 32, 0ull, 0ull, 0ull);
        hipLaunchKernelGGL(softmax4096, dim3(S), blk, 0, stream,
            sc, qk + (size_t)b * BBLK_E);           // P_b overwrites its block
    }

    // ---- batched PV: grid (256, 1, 4) ----
    hipLaunchKernelGGL(gemm_pv, dim3(256, 1, 4), blk, 0, stream,
        qk, nul16, vT,
        S, S, B * S, (const float*)nullptr,
        out, (u16*)nullptr, H, 8,
        (unsigned long long)BBLK_E, 4096ull, (unsigned long long)S * H);
}